// Round 12
// baseline (436.171 us; speedup 1.0000x reference)
//
#include <hip/hip_runtime.h>

#define T 32
#define C 2048
#define NTOT 600
#define NCLASS 20
#define NSUP 5
#define PER 30
#define NQPC 25
#define NQ 500
#define NQROWS (NQ * T)      // 16000
#define NPROWS (NCLASS * T)  // 640
#define GAMMA 0.1f
#define INVG 10.0f
#define BIG 1e10f
#define NMM (NQ * NCLASS + NQ + NCLASS)  // 10520
#define GEMM_BLKS 1250      // 625 tiles x 2 K-halves
#define SYRK_BLKS_PAD 136   // multiple of 8 so gemm swizzle sees o%8 unchanged
#define STAGE_BLKS_A 2000   // (16000/16 rows) x 2 halves
#define STAGE_BLKS_B 80     // (640/16) x 2

typedef __fp16 half8 __attribute__((ext_vector_type(8)));
typedef float f32x4 __attribute__((ext_vector_type(4)));

// ---------------- parallel stable counting sort (1 block) ----------------
__global__ __launch_bounds__(640) void sort_kernel(const int* __restrict__ target,
                                                   int* __restrict__ order,
                                                   int* __restrict__ qsrc) {
    __shared__ int tgt[NTOT];
    __shared__ int offs[NCLASS];
    __shared__ int ordl[NTOT];
    int tid = threadIdx.x;
    if (tid < NTOT) tgt[tid] = target[tid];
    __syncthreads();
    if (tid < NCLASS) {
        int o = 0;
        for (int i = 0; i < NTOT; i++) o += (tgt[i] < tid) ? 1 : 0;
        offs[tid] = o;
    }
    __syncthreads();
    if (tid < NTOT) {
        int c = tgt[tid];
        int rank = 0;
        for (int k = 0; k < NTOT; k++) rank += (k < tid && tgt[k] == c) ? 1 : 0;
        ordl[offs[c] + rank] = tid;
    }
    __syncthreads();
    if (tid < NTOT) order[tid] = ordl[tid];
    if (tid < NQ) qsrc[tid] = ordl[(tid / NQPC) * PER + NSUP + (tid % NQPC)];
}

// ---------------- streaming staging: gather/mean + f16 split (R10 mapping) --------
// A side: hi only (f16 rounding). B side: hi + lo. CHUNK-MAJOR dst[chunk*nrows+row].
__global__ __launch_bounds__(512) void stage_kernel(const float* __restrict__ inp,
                                                    const int* __restrict__ qsrc,
                                                    const int* __restrict__ order,
                                                    half8* __restrict__ Ah,
                                                    half8* __restrict__ Bh,
                                                    half8* __restrict__ Bl) {
    int bid = blockIdx.x;
    int tid = threadIdx.x;
    int row = tid & 15, seg = tid >> 4;  // seg 0..31
    bool isA = bid < STAGE_BLKS_A;
    int b = isA ? bid : bid - STAGE_BLKS_A;
    int rowblk = b >> 1, half = b & 1;
    int rowg = rowblk * 16 + row;
    int col0 = half * 1024 + seg * 32;
    int chunk0 = half * 128 + seg * 4;
    float vals[32];
    if (isA) {
        const float* src = inp + (size_t)qsrc[rowg >> 5] * (T * C) + (size_t)(rowg & 31) * C + col0;
#pragma unroll
        for (int i = 0; i < 8; i++) {
            float4 v = *(const float4*)(src + i * 4);
            vals[i * 4 + 0] = v.x; vals[i * 4 + 1] = v.y;
            vals[i * 4 + 2] = v.z; vals[i * 4 + 3] = v.w;
        }
        half8 hv[4];
#pragma unroll
        for (int e = 0; e < 32; e++) hv[e >> 3][e & 7] = (__fp16)vals[e];
#pragma unroll
        for (int c = 0; c < 4; c++) Ah[(size_t)(chunk0 + c) * NQROWS + rowg] = hv[c];
    } else {
        int cls = rowg >> 5, trow = rowg & 31;
        const float* base = inp + (size_t)trow * C + col0;
        const float* s0 = base + (size_t)order[cls * PER + 0] * (T * C);
        const float* s1 = base + (size_t)order[cls * PER + 1] * (T * C);
        const float* s2 = base + (size_t)order[cls * PER + 2] * (T * C);
        const float* s3 = base + (size_t)order[cls * PER + 3] * (T * C);
        const float* s4 = base + (size_t)order[cls * PER + 4] * (T * C);
#pragma unroll
        for (int i = 0; i < 8; i++) {
            float4 a = *(const float4*)(s0 + i * 4);
            float4 b4 = *(const float4*)(s1 + i * 4);
            float4 c = *(const float4*)(s2 + i * 4);
            float4 d = *(const float4*)(s3 + i * 4);
            float4 e = *(const float4*)(s4 + i * 4);
            vals[i * 4 + 0] = (a.x + b4.x + c.x + d.x + e.x) * 0.2f;
            vals[i * 4 + 1] = (a.y + b4.y + c.y + d.y + e.y) * 0.2f;
            vals[i * 4 + 2] = (a.z + b4.z + c.z + d.z + e.z) * 0.2f;
            vals[i * 4 + 3] = (a.w + b4.w + c.w + d.w + e.w) * 0.2f;
        }
        half8 hv[4], lv[4];
#pragma unroll
        for (int e = 0; e < 32; e++) {
            float f = vals[e];
            __fp16 h = (__fp16)f;
            hv[e >> 3][e & 7] = h;
            lv[e >> 3][e & 7] = (__fp16)(f - (float)h);
        }
#pragma unroll
        for (int c = 0; c < 4; c++) {
            size_t o = (size_t)(chunk0 + c) * NPROWS + rowg;
            Bh[o] = hv[c];
            Bl[o] = lv[c];
        }
    }
}

// ---------------- merged: SYRK (blocks 0..135) + split-K register-direct f16 GEMM --
// GEMM: NO LDS, NO barriers (R10 structure, compiler-scheduled). Split-K x2 doubles
// resident waves (grid 761 -> 1386) to hide L2 latency; halves write to xy0/xy1.
__global__ __launch_bounds__(256) void gemm_syrk_kernel(const half8* __restrict__ Ah,
                                                        const half8* __restrict__ Bh,
                                                        const half8* __restrict__ Bl,
                                                        float* __restrict__ xy0,
                                                        float* __restrict__ xy1,
                                                        float* __restrict__ gxx,
                                                        float* __restrict__ gyy) {
    int tid = threadIdx.x, lane = tid & 63, wid = tid >> 6;
    int o = blockIdx.x;
    int g = lane >> 4, r = lane & 15;
    if (o < SYRK_BLKS_PAD) {
        // ---- SYRK path: one wave per 32x32 Gram matrix (short blocks first) ----
        int ww = o * 4 + wid;
        if (ww >= NQ + NCLASS) return;
        f32x4 acc[2][2];
        f32x4 zero = {0.f, 0.f, 0.f, 0.f};
        acc[0][0] = zero; acc[0][1] = zero; acc[1][0] = zero; acc[1][1] = zero;
        float* outp;
        if (ww < NQ) {
            // gxx = Ah Ah^T  (1-term: self-consistent with 2-term xy)
            int row0 = ww * 32;
            outp = gxx + (size_t)ww * (T * T);
            for (int t = 0; t < C / 32; t++) {
                size_t base = (size_t)(t * 4 + g) * NQROWS + row0 + r;
                half8 h0 = Ah[base], h1 = Ah[base + 16];
                acc[0][0] = __builtin_amdgcn_mfma_f32_16x16x32_f16(h0, h0, acc[0][0], 0, 0, 0);
                acc[0][1] = __builtin_amdgcn_mfma_f32_16x16x32_f16(h0, h1, acc[0][1], 0, 0, 0);
                acc[1][0] = __builtin_amdgcn_mfma_f32_16x16x32_f16(h1, h0, acc[1][0], 0, 0, 0);
                acc[1][1] = __builtin_amdgcn_mfma_f32_16x16x32_f16(h1, h1, acc[1][1], 0, 0, 0);
            }
        } else {
            // gyy = (Bh+Bl)(Bh+Bl)^T, 3-term
            int row0 = (ww - NQ) * 32;
            outp = gyy + (size_t)(ww - NQ) * (T * T);
            for (int t = 0; t < C / 32; t++) {
                size_t base = (size_t)(t * 4 + g) * NPROWS + row0 + r;
                half8 h0 = Bh[base], h1 = Bh[base + 16];
                half8 l0 = Bl[base], l1 = Bl[base + 16];
                acc[0][0] = __builtin_amdgcn_mfma_f32_16x16x32_f16(h0, h0, acc[0][0], 0, 0, 0);
                acc[0][0] = __builtin_amdgcn_mfma_f32_16x16x32_f16(h0, l0, acc[0][0], 0, 0, 0);
                acc[0][0] = __builtin_amdgcn_mfma_f32_16x16x32_f16(l0, h0, acc[0][0], 0, 0, 0);
                acc[0][1] = __builtin_amdgcn_mfma_f32_16x16x32_f16(h0, h1, acc[0][1], 0, 0, 0);
                acc[0][1] = __builtin_amdgcn_mfma_f32_16x16x32_f16(h0, l1, acc[0][1], 0, 0, 0);
                acc[0][1] = __builtin_amdgcn_mfma_f32_16x16x32_f16(l0, h1, acc[0][1], 0, 0, 0);
                acc[1][0] = __builtin_amdgcn_mfma_f32_16x16x32_f16(h1, h0, acc[1][0], 0, 0, 0);
                acc[1][0] = __builtin_amdgcn_mfma_f32_16x16x32_f16(h1, l0, acc[1][0], 0, 0, 0);
                acc[1][0] = __builtin_amdgcn_mfma_f32_16x16x32_f16(l1, h0, acc[1][0], 0, 0, 0);
                acc[1][1] = __builtin_amdgcn_mfma_f32_16x16x32_f16(h1, h1, acc[1][1], 0, 0, 0);
                acc[1][1] = __builtin_amdgcn_mfma_f32_16x16x32_f16(h1, l1, acc[1][1], 0, 0, 0);
                acc[1][1] = __builtin_amdgcn_mfma_f32_16x16x32_f16(l1, h1, acc[1][1], 0, 0, 0);
            }
        }
#pragma unroll
        for (int mi = 0; mi < 2; mi++)
#pragma unroll
            for (int ni = 0; ni < 2; ni++)
#pragma unroll
                for (int j = 0; j < 4; j++)
                    outp[(mi * 16 + g * 4 + j) * T + ni * 16 + r] = acc[mi][ni][j];
        return;
    }
    // ---- GEMM path: xy_k = Ah*(Bh+Bl)^T over K-half, 2 MFMA terms, reg-direct ----
    int oo = o - SYRK_BLKS_PAD;  // 0..1249; SYRK_BLKS_PAD%8==0 keeps oo%8==o%8
    // bijective XCD swizzle over 1250 = 8*156+2 (m204 formula)
    int xcd = oo & 7, slot = oo >> 3;
    int v = (xcd < 2 ? xcd * 157 : 2 * 157 + (xcd - 2) * 156) + slot;
    int ks = v >= 625 ? 1 : 0;     // K-half
    int vv = v - ks * 625;
    int bm = vv / 5, bn = vv % 5;
    int wr = wid >> 1, wc = wid & 1;
    int m0 = bm * 128 + wr * 64, n0 = bn * 128 + wc * 64;  // this wave's 64x64 tile
    const half8* pA = Ah + (size_t)(ks * 128 + g) * NQROWS + m0 + r;
    const half8* pBh = Bh + (size_t)(ks * 128 + g) * NPROWS + n0 + r;
    const half8* pBl = Bl + (size_t)(ks * 128 + g) * NPROWS + n0 + r;
    float* xyp = ks ? xy1 : xy0;
    f32x4 acc[4][4];
    f32x4 zero = {0.f, 0.f, 0.f, 0.f};
#pragma unroll
    for (int mi = 0; mi < 4; mi++)
#pragma unroll
        for (int ni = 0; ni < 4; ni++) acc[mi][ni] = zero;
#pragma unroll 2
    for (int t = 0; t < C / 64; t++) {
        half8 ah[4], bh[4], bl[4];
#pragma unroll
        for (int i = 0; i < 4; i++) {
            ah[i] = pA[i * 16];    // imm offsets 0,256,512,768 B
            bh[i] = pBh[i * 16];
            bl[i] = pBl[i * 16];
        }
        pA += 4 * NQROWS;
        pBh += 4 * NPROWS;
        pBl += 4 * NPROWS;
#pragma unroll
        for (int mi = 0; mi < 4; mi++)
#pragma unroll
            for (int ni = 0; ni < 4; ni++) {
                acc[mi][ni] = __builtin_amdgcn_mfma_f32_16x16x32_f16(ah[mi], bh[ni], acc[mi][ni], 0, 0, 0);
                acc[mi][ni] = __builtin_amdgcn_mfma_f32_16x16x32_f16(ah[mi], bl[ni], acc[mi][ni], 0, 0, 0);
            }
    }
    int orow = m0 + g * 4;
    int ocol = n0 + r;
#pragma unroll
    for (int mi = 0; mi < 4; mi++)
#pragma unroll
        for (int ni = 0; ni < 4; ni++)
#pragma unroll
            for (int j = 0; j < 4; j++)
                xyp[(size_t)(orow + mi * 16 + j) * NPROWS + ocol + ni * 16] = acc[mi][ni][j];
}

// ---------------- extract row norms from Gram diagonals ----------------
__global__ void diag_kernel(const float* __restrict__ gxx, const float* __restrict__ gyy,
                            float* __restrict__ x2, float* __restrict__ y2) {
    int i = blockIdx.x * 256 + threadIdx.x;
    if (i < NQROWS) {
        x2[i] = gxx[(size_t)(i >> 5) * (T * T) + (i & 31) * (T + 1)];
    } else if (i < NQROWS + NPROWS) {
        int j = i - NQROWS;
        y2[j] = gyy[(size_t)(j >> 5) * (T * T) + (j & 31) * (T + 1)];
    }
}

// ---------------- wavefront soft-DTW: 32 lanes = 32 columns, 2 matrices/wave ------
// Cross-mode cost = xy0 + xy1 (split-K halves summed during the streaming read).
__global__ __launch_bounds__(256) void softdtw_wave_kernel(
        const float* __restrict__ xy0, const float* __restrict__ xy1,
        const float* __restrict__ gxx, const float* __restrict__ gyy,
        const float* __restrict__ x2, const float* __restrict__ y2,
        float* __restrict__ dxy, float* __restrict__ dxx, float* __restrict__ dyy) {
    int tid = threadIdx.x;
    int j = tid & 31;                       // column within the matrix
    int mm = blockIdx.x * 8 + (tid >> 5);   // 8 matrices per 256-thread block
    bool valid = mm < NMM;
    int mmc = valid ? mm : 0;
    const float* rterm;
    const float* cterm;
    const float* cptr;
    const float* cptr2 = nullptr;           // second K-half (cross mode only)
    int cstride;
    float* outp;
    if (mmc < NQ * NCLASS) {
        int q = mmc / NCLASS, m = mmc % NCLASS;
        rterm = x2 + q * T;
        cterm = y2 + m * T;
        size_t offb = (size_t)(q * T) * NPROWS + m * T;
        cptr = xy0 + offb;
        cptr2 = xy1 + offb;
        cstride = NPROWS;
        outp = dxy + mmc;
    } else if (mmc < NQ * NCLASS + NQ) {
        int i = mmc - NQ * NCLASS;
        rterm = x2 + i * T;
        cterm = rterm;
        cptr = gxx + (size_t)i * (T * T);
        cstride = T;
        outp = dxx + i;
    } else {
        int i = mmc - NQ * NCLASS - NQ;
        rterm = y2 + i * T;
        cterm = rterm;
        cptr = gyy + (size_t)i * (T * T);
        cstride = T;
        outp = dyy + i;
    }
    float cjv = cterm[j];      // column term (lane-resident)
    float xreg = rterm[j];     // lane l holds rterm[l]; shuffled per step
    float my_prev = BIG, my_prev2 = BIG;
    int ip = 0 - j; ip = ip < 0 ? 0 : (ip > 31 ? 31 : ip);
    float nxt_xy = cptr[(size_t)ip * cstride + j];
    if (cptr2) nxt_xy += cptr2[(size_t)ip * cstride + j];
    for (int k = 0; k < 63; k++) {
        float cur_xy = nxt_xy;
        int in = k + 1 - j; in = in < 0 ? 0 : (in > 31 ? 31 : in);
        nxt_xy = cptr[(size_t)in * cstride + j];   // prefetch next anti-diagonal
        if (cptr2) nxt_xy += cptr2[(size_t)in * cstride + j];
        float lp = __shfl_up(my_prev, 1, 32);
        float dg = __shfl_up(my_prev2, 1, 32);
        if (j == 0) { lp = BIG; dg = (k == 0) ? 0.f : BIG; }
        float up = my_prev;
        int i = k - j;
        float ai = __shfl(xreg, i & 31, 32);
        float d = ai + cjv - 2.0f * cur_xy;
        float mn = fminf(dg, fminf(up, lp));
        float ssum = __expf((mn - dg) * INVG) + __expf((mn - up) * INVG) +
                     __expf((mn - lp) * INVG);
        float r = d + mn - GAMMA * __logf(ssum);
        bool active = (i >= 0) && (i < 32);
        my_prev2 = my_prev;
        my_prev = active ? r : my_prev;
    }
    if (j == 31 && valid) *outp = my_prev;  // R[31][31]
}

// ---------------- finalize: dist, log-softmax, loss, acc ----------------
__global__ __launch_bounds__(512) void finalize_kernel(const float* __restrict__ dxy,
                                                       const float* __restrict__ dxx,
                                                       const float* __restrict__ dyy,
                                                       float* __restrict__ out) {
    __shared__ float sl[512];
    __shared__ float sa[512];
    int q = threadIdx.x;
    float bl = 0.f, fl = 0.f;
    if (q < NQ) {
        float dxxq = dxx[q];
        int cq = q / NQPC;
        float dd[NCLASS];
#pragma unroll
        for (int m = 0; m < NCLASS; m++)
            dd[m] = dxy[q * NCLASS + m] - 0.5f * (dxxq + dyy[m]);
        float best = dd[0];
        int bi = 0;
#pragma unroll
        for (int m = 1; m < NCLASS; m++) {
            if (dd[m] < best) { best = dd[m]; bi = m; }
        }
        float s = 0.f;
        float dcq = dd[0];
#pragma unroll
        for (int m = 0; m < NCLASS; m++) {
            s += __expf(best - dd[m]);
            if (m == cq) dcq = dd[m];
        }
        float lse = __logf(s) - best;
        bl = dcq + lse;
        out[2 + q] = bl;
        fl = (bi == cq) ? 1.f : 0.f;
    }
    sl[threadIdx.x] = bl;
    sa[threadIdx.x] = fl;
    __syncthreads();
    for (int off = 256; off; off >>= 1) {
        if (threadIdx.x < off) {
            sl[threadIdx.x] += sl[threadIdx.x + off];
            sa[threadIdx.x] += sa[threadIdx.x + off];
        }
        __syncthreads();
    }
    if (threadIdx.x == 0) {
        out[0] = sl[0] / (float)NQ;
        out[1] = sa[0] / (float)NQ;
    }
}

extern "C" void kernel_launch(void* const* d_in, const int* in_sizes, int n_in,
                              void* d_out, int out_size, void* d_ws, size_t ws_size,
                              hipStream_t stream) {
    const float* inp = (const float*)d_in[0];
    const int* target = (const int*)d_in[1];
    float* out = (float*)d_out;
    char* ws = (char*)d_ws;

    size_t off = 0;
    auto carve = [&](size_t bytes) {
        void* p = ws + off;
        off = (off + bytes + 255) & ~(size_t)255;
        return p;
    };
    int* order = (int*)carve(NTOT * sizeof(int));
    int* qsrc = (int*)carve(NQ * sizeof(int));
    float* x2 = (float*)carve((size_t)NQROWS * sizeof(float));
    float* y2 = (float*)carve((size_t)NPROWS * sizeof(float));
    float* xy0 = (float*)carve((size_t)NQROWS * NPROWS * sizeof(float));  // 41 MB
    float* xy1 = (float*)carve((size_t)NQROWS * NPROWS * sizeof(float));  // 41 MB
    float* gxx = (float*)carve((size_t)NQ * T * T * sizeof(float));
    float* gyy = (float*)carve((size_t)NCLASS * T * T * sizeof(float));
    float* dxy = (float*)carve((size_t)NQ * NCLASS * sizeof(float));
    float* dxx = (float*)carve((size_t)NQ * sizeof(float));
    float* dyy = (float*)carve((size_t)NCLASS * sizeof(float));
    half8* Ah = (half8*)carve((size_t)(C / 8) * NQROWS * 16);  // 65.5 MB chunk-major
    half8* Bh = (half8*)carve((size_t)(C / 8) * NPROWS * 16);  // 2.6 MB
    half8* Bl = (half8*)carve((size_t)(C / 8) * NPROWS * 16);
    (void)ws_size;  // ~157 MB total

    sort_kernel<<<1, 640, 0, stream>>>(target, order, qsrc);
    stage_kernel<<<STAGE_BLKS_A + STAGE_BLKS_B, 512, 0, stream>>>(inp, qsrc, order, Ah, Bh, Bl);
    gemm_syrk_kernel<<<SYRK_BLKS_PAD + GEMM_BLKS, 256, 0, stream>>>(Ah, Bh, Bl, xy0, xy1, gxx, gyy);
    diag_kernel<<<(NQROWS + NPROWS + 255) / 256, 256, 0, stream>>>(gxx, gyy, x2, y2);
    softdtw_wave_kernel<<<(NMM + 7) / 8, 256, 0, stream>>>(xy0, xy1, gxx, gyy, x2, y2, dxy, dxx, dyy);
    finalize_kernel<<<1, 512, 0, stream>>>(dxy, dxx, dyy, out);
}

// Round 13
// 403.000 us; speedup vs baseline: 1.0823x; 1.0823x over previous
//
#include <hip/hip_runtime.h>

#define T 32
#define C 2048
#define NTOT 600
#define NCLASS 20
#define NSUP 5
#define PER 30
#define NQPC 25
#define NQ 500
#define NQROWS (NQ * T)      // 16000
#define NPROWS (NCLASS * T)  // 640
#define GAMMA 0.1f
#define INVG 10.0f
#define BIG 1e10f
#define NMM (NQ * NCLASS + NQ + NCLASS)  // 10520
#define GEMM_BLKS 625
#define SYRK_BLKS_PAD 136  // multiple of 8 so gemm swizzle sees o%8 unchanged
#define STAGE_BLKS ((NQROWS + NPROWS) / 8)  // 2080 (8 waves/block, wave = one row)

typedef __fp16 half8 __attribute__((ext_vector_type(8)));
typedef float f32x4 __attribute__((ext_vector_type(4)));

// ---------------- parallel stable counting sort (1 block) ----------------
__global__ __launch_bounds__(640) void sort_kernel(const int* __restrict__ target,
                                                   int* __restrict__ order,
                                                   int* __restrict__ qsrc) {
    __shared__ int tgt[NTOT];
    __shared__ int offs[NCLASS];
    __shared__ int ordl[NTOT];
    int tid = threadIdx.x;
    if (tid < NTOT) tgt[tid] = target[tid];
    __syncthreads();
    if (tid < NCLASS) {
        int o = 0;
        for (int i = 0; i < NTOT; i++) o += (tgt[i] < tid) ? 1 : 0;
        offs[tid] = o;
    }
    __syncthreads();
    if (tid < NTOT) {
        int c = tgt[tid];
        int rank = 0;
        for (int k = 0; k < NTOT; k++) rank += (k < tid && tgt[k] == c) ? 1 : 0;
        ordl[offs[c] + rank] = tid;
    }
    __syncthreads();
    if (tid < NTOT) order[tid] = ordl[tid];
    if (tid < NQ) qsrc[tid] = ordl[(tid / NQPC) * PER + NSUP + (tid % NQPC)];
}

// ---------------- streaming staging: gather/mean + f16 split, ROW-MAJOR -----------
// Staged layout: dst[row * 256 + chunk] (half8 = cols chunk*8..+8). Wave = one row:
// lane reads 128B of the 8KB source row (coalesced 8KB/wave), writes 64B at
// row*512B + lane*64B (coalesced 4KB/wave). No LDS, no transpose.
__global__ __launch_bounds__(512) void stage_kernel(const float* __restrict__ inp,
                                                    const int* __restrict__ qsrc,
                                                    const int* __restrict__ order,
                                                    half8* __restrict__ Ah,
                                                    half8* __restrict__ Bh,
                                                    half8* __restrict__ Bl) {
    int w = blockIdx.x * 8 + (threadIdx.x >> 6);  // global wave id = staged row
    int lane = threadIdx.x & 63;
    int col0 = lane * 32;
    if (w < NQROWS) {
        const float* src = inp + (size_t)qsrc[w >> 5] * (T * C) + (size_t)(w & 31) * C + col0;
        float vals[32];
#pragma unroll
        for (int i = 0; i < 8; i++) {
            float4 v = *(const float4*)(src + i * 4);
            vals[i * 4 + 0] = v.x; vals[i * 4 + 1] = v.y;
            vals[i * 4 + 2] = v.z; vals[i * 4 + 3] = v.w;
        }
        half8 hv[4];
#pragma unroll
        for (int e = 0; e < 32; e++) hv[e >> 3][e & 7] = (__fp16)vals[e];
        half8* d = Ah + (size_t)w * 256 + lane * 4;
#pragma unroll
        for (int c = 0; c < 4; c++) d[c] = hv[c];
    } else {
        int m = w - NQROWS;  // proto row 0..639
        int cls = m >> 5, trow = m & 31;
        const float* base = inp + (size_t)trow * C + col0;
        const float* s0 = base + (size_t)order[cls * PER + 0] * (T * C);
        const float* s1 = base + (size_t)order[cls * PER + 1] * (T * C);
        const float* s2 = base + (size_t)order[cls * PER + 2] * (T * C);
        const float* s3 = base + (size_t)order[cls * PER + 3] * (T * C);
        const float* s4 = base + (size_t)order[cls * PER + 4] * (T * C);
        float vals[32];
#pragma unroll
        for (int i = 0; i < 8; i++) {
            float4 a = *(const float4*)(s0 + i * 4);
            float4 b4 = *(const float4*)(s1 + i * 4);
            float4 c = *(const float4*)(s2 + i * 4);
            float4 d = *(const float4*)(s3 + i * 4);
            float4 e = *(const float4*)(s4 + i * 4);
            vals[i * 4 + 0] = (a.x + b4.x + c.x + d.x + e.x) * 0.2f;
            vals[i * 4 + 1] = (a.y + b4.y + c.y + d.y + e.y) * 0.2f;
            vals[i * 4 + 2] = (a.z + b4.z + c.z + d.z + e.z) * 0.2f;
            vals[i * 4 + 3] = (a.w + b4.w + c.w + d.w + e.w) * 0.2f;
        }
        half8 hv[4], lv[4];
#pragma unroll
        for (int e = 0; e < 32; e++) {
            float f = vals[e];
            __fp16 h = (__fp16)f;
            hv[e >> 3][e & 7] = h;
            lv[e >> 3][e & 7] = (__fp16)(f - (float)h);
        }
        half8* dh = Bh + (size_t)m * 256 + lane * 4;
        half8* dl = Bl + (size_t)m * 256 + lane * 4;
#pragma unroll
        for (int c = 0; c < 4; c++) { dh[c] = hv[c]; dl[c] = lv[c]; }
    }
}

// ---------------- merged: SYRK (blocks 0..135) + register-direct f16 GEMM ----------
// Operands ROW-MAJOR [row][256]. GEMM: NO LDS, NO barriers (R10 structure).
// Fragment load = 16 clusters x 64B = 16 full lines/instr (same as chunk-major).
__global__ __launch_bounds__(256) void gemm_syrk_kernel(const half8* __restrict__ Ah,
                                                        const half8* __restrict__ Bh,
                                                        const half8* __restrict__ Bl,
                                                        float* __restrict__ xy,
                                                        float* __restrict__ gxx,
                                                        float* __restrict__ gyy) {
    int tid = threadIdx.x, lane = tid & 63, wid = tid >> 6;
    int o = blockIdx.x;
    int g = lane >> 4, r = lane & 15;
    if (o < SYRK_BLKS_PAD) {
        // ---- SYRK path: one wave per 32x32 Gram matrix (short blocks first) ----
        int ww = o * 4 + wid;
        if (ww >= NQ + NCLASS) return;
        f32x4 acc[2][2];
        f32x4 zero = {0.f, 0.f, 0.f, 0.f};
        acc[0][0] = zero; acc[0][1] = zero; acc[1][0] = zero; acc[1][1] = zero;
        float* outp;
        if (ww < NQ) {
            // gxx = Ah Ah^T  (1-term: self-consistent with 2-term xy)
            int row0 = ww * 32;
            outp = gxx + (size_t)ww * (T * T);
            const half8* p0 = Ah + (size_t)(row0 + r) * 256 + g;
            const half8* p1 = p0 + 16 * 256;
            for (int t = 0; t < C / 32; t++) {
                half8 h0 = *p0, h1 = *p1;
                p0 += 4; p1 += 4;
                acc[0][0] = __builtin_amdgcn_mfma_f32_16x16x32_f16(h0, h0, acc[0][0], 0, 0, 0);
                acc[0][1] = __builtin_amdgcn_mfma_f32_16x16x32_f16(h0, h1, acc[0][1], 0, 0, 0);
                acc[1][0] = __builtin_amdgcn_mfma_f32_16x16x32_f16(h1, h0, acc[1][0], 0, 0, 0);
                acc[1][1] = __builtin_amdgcn_mfma_f32_16x16x32_f16(h1, h1, acc[1][1], 0, 0, 0);
            }
        } else {
            // gyy = (Bh+Bl)(Bh+Bl)^T, 3-term
            int row0 = (ww - NQ) * 32;
            outp = gyy + (size_t)(ww - NQ) * (T * T);
            const half8* ph0 = Bh + (size_t)(row0 + r) * 256 + g;
            const half8* ph1 = ph0 + 16 * 256;
            const half8* pl0 = Bl + (size_t)(row0 + r) * 256 + g;
            const half8* pl1 = pl0 + 16 * 256;
            for (int t = 0; t < C / 32; t++) {
                half8 h0 = *ph0, h1 = *ph1, l0 = *pl0, l1 = *pl1;
                ph0 += 4; ph1 += 4; pl0 += 4; pl1 += 4;
                acc[0][0] = __builtin_amdgcn_mfma_f32_16x16x32_f16(h0, h0, acc[0][0], 0, 0, 0);
                acc[0][0] = __builtin_amdgcn_mfma_f32_16x16x32_f16(h0, l0, acc[0][0], 0, 0, 0);
                acc[0][0] = __builtin_amdgcn_mfma_f32_16x16x32_f16(l0, h0, acc[0][0], 0, 0, 0);
                acc[0][1] = __builtin_amdgcn_mfma_f32_16x16x32_f16(h0, h1, acc[0][1], 0, 0, 0);
                acc[0][1] = __builtin_amdgcn_mfma_f32_16x16x32_f16(h0, l1, acc[0][1], 0, 0, 0);
                acc[0][1] = __builtin_amdgcn_mfma_f32_16x16x32_f16(l0, h1, acc[0][1], 0, 0, 0);
                acc[1][0] = __builtin_amdgcn_mfma_f32_16x16x32_f16(h1, h0, acc[1][0], 0, 0, 0);
                acc[1][0] = __builtin_amdgcn_mfma_f32_16x16x32_f16(h1, l0, acc[1][0], 0, 0, 0);
                acc[1][0] = __builtin_amdgcn_mfma_f32_16x16x32_f16(l1, h0, acc[1][0], 0, 0, 0);
                acc[1][1] = __builtin_amdgcn_mfma_f32_16x16x32_f16(h1, h1, acc[1][1], 0, 0, 0);
                acc[1][1] = __builtin_amdgcn_mfma_f32_16x16x32_f16(h1, l1, acc[1][1], 0, 0, 0);
                acc[1][1] = __builtin_amdgcn_mfma_f32_16x16x32_f16(l1, h1, acc[1][1], 0, 0, 0);
            }
        }
#pragma unroll
        for (int mi = 0; mi < 2; mi++)
#pragma unroll
            for (int ni = 0; ni < 2; ni++)
#pragma unroll
                for (int j = 0; j < 4; j++)
                    outp[(mi * 16 + g * 4 + j) * T + ni * 16 + r] = acc[mi][ni][j];
        return;
    }
    // ---- GEMM path: xy = Ah*(Bh+Bl)^T, 2 MFMA terms, register-direct ----
    int oo = o - SYRK_BLKS_PAD;  // 0..624; SYRK_BLKS_PAD%8==0 keeps oo%8==o%8
    int xcd = oo & 7, slot = oo >> 3;
    int v = (xcd < 1 ? xcd * 79 : 79 + (xcd - 1) * 78) + slot;  // bijective over 625=8*78+1
    int bm = v / 5, bn = v % 5;
    int wr = wid >> 1, wc = wid & 1;
    int m0 = bm * 128 + wr * 64, n0 = bn * 128 + wc * 64;  // this wave's 64x64 tile
    const half8* pA = Ah + (size_t)(m0 + r) * 256 + g;
    const half8* pBh = Bh + (size_t)(n0 + r) * 256 + g;
    const half8* pBl = Bl + (size_t)(n0 + r) * 256 + g;
    f32x4 acc[4][4];
    f32x4 zero = {0.f, 0.f, 0.f, 0.f};
#pragma unroll
    for (int mi = 0; mi < 4; mi++)
#pragma unroll
        for (int ni = 0; ni < 4; ni++) acc[mi][ni] = zero;
#pragma unroll 2
    for (int t = 0; t < C / 32; t++) {
        half8 ah[4], bh[4], bl[4];
#pragma unroll
        for (int i = 0; i < 4; i++) {
            ah[i] = pA[(size_t)i * (16 * 256)];   // fragment rows 16 apart
            bh[i] = pBh[(size_t)i * (16 * 256)];
            bl[i] = pBl[(size_t)i * (16 * 256)];
        }
        pA += 4;   // next 4 chunks (64B) of each row
        pBh += 4;
        pBl += 4;
#pragma unroll
        for (int mi = 0; mi < 4; mi++)
#pragma unroll
            for (int ni = 0; ni < 4; ni++) {
                acc[mi][ni] = __builtin_amdgcn_mfma_f32_16x16x32_f16(ah[mi], bh[ni], acc[mi][ni], 0, 0, 0);
                acc[mi][ni] = __builtin_amdgcn_mfma_f32_16x16x32_f16(ah[mi], bl[ni], acc[mi][ni], 0, 0, 0);
            }
    }
    int orow = m0 + g * 4;
    int ocol = n0 + r;
#pragma unroll
    for (int mi = 0; mi < 4; mi++)
#pragma unroll
        for (int ni = 0; ni < 4; ni++)
#pragma unroll
            for (int j = 0; j < 4; j++)
                xy[(size_t)(orow + mi * 16 + j) * NPROWS + ocol + ni * 16] = acc[mi][ni][j];
}

// ---------------- extract row norms from Gram diagonals ----------------
__global__ void diag_kernel(const float* __restrict__ gxx, const float* __restrict__ gyy,
                            float* __restrict__ x2, float* __restrict__ y2) {
    int i = blockIdx.x * 256 + threadIdx.x;
    if (i < NQROWS) {
        x2[i] = gxx[(size_t)(i >> 5) * (T * T) + (i & 31) * (T + 1)];
    } else if (i < NQROWS + NPROWS) {
        int j = i - NQROWS;
        y2[j] = gyy[(size_t)(j >> 5) * (T * T) + (j & 31) * (T + 1)];
    }
}

// ---------------- wavefront soft-DTW: 32 lanes = 32 columns, 2 matrices/wave ------
__global__ __launch_bounds__(256) void softdtw_wave_kernel(
        const float* __restrict__ xy, const float* __restrict__ gxx,
        const float* __restrict__ gyy, const float* __restrict__ x2,
        const float* __restrict__ y2, float* __restrict__ dxy,
        float* __restrict__ dxx, float* __restrict__ dyy) {
    int tid = threadIdx.x;
    int j = tid & 31;                       // column within the matrix
    int mm = blockIdx.x * 8 + (tid >> 5);   // 8 matrices per 256-thread block
    bool valid = mm < NMM;
    int mmc = valid ? mm : 0;
    const float* rterm;
    const float* cterm;
    const float* cptr;
    int cstride;
    float* outp;
    if (mmc < NQ * NCLASS) {
        int q = mmc / NCLASS, m = mmc % NCLASS;
        rterm = x2 + q * T;
        cterm = y2 + m * T;
        cptr = xy + (size_t)(q * T) * NPROWS + m * T;
        cstride = NPROWS;
        outp = dxy + mmc;
    } else if (mmc < NQ * NCLASS + NQ) {
        int i = mmc - NQ * NCLASS;
        rterm = x2 + i * T;
        cterm = rterm;
        cptr = gxx + (size_t)i * (T * T);
        cstride = T;
        outp = dxx + i;
    } else {
        int i = mmc - NQ * NCLASS - NQ;
        rterm = y2 + i * T;
        cterm = rterm;
        cptr = gyy + (size_t)i * (T * T);
        cstride = T;
        outp = dyy + i;
    }
    float cjv = cterm[j];      // column term (lane-resident)
    float xreg = rterm[j];     // lane l holds rterm[l]; shuffled per step
    float my_prev = BIG, my_prev2 = BIG;
    int ip = 0 - j; ip = ip < 0 ? 0 : (ip > 31 ? 31 : ip);
    float nxt_xy = cptr[(size_t)ip * cstride + j];
    for (int k = 0; k < 63; k++) {
        float cur_xy = nxt_xy;
        int in = k + 1 - j; in = in < 0 ? 0 : (in > 31 ? 31 : in);
        nxt_xy = cptr[(size_t)in * cstride + j];   // prefetch next anti-diagonal
        float lp = __shfl_up(my_prev, 1, 32);
        float dg = __shfl_up(my_prev2, 1, 32);
        if (j == 0) { lp = BIG; dg = (k == 0) ? 0.f : BIG; }
        float up = my_prev;
        int i = k - j;
        float ai = __shfl(xreg, i & 31, 32);
        float d = ai + cjv - 2.0f * cur_xy;
        float mn = fminf(dg, fminf(up, lp));
        float ssum = __expf((mn - dg) * INVG) + __expf((mn - up) * INVG) +
                     __expf((mn - lp) * INVG);
        float r = d + mn - GAMMA * __logf(ssum);
        bool active = (i >= 0) && (i < 32);
        my_prev2 = my_prev;
        my_prev = active ? r : my_prev;
    }
    if (j == 31 && valid) *outp = my_prev;  // R[31][31]
}

// ---------------- finalize: dist, log-softmax, loss, acc ----------------
__global__ __launch_bounds__(512) void finalize_kernel(const float* __restrict__ dxy,
                                                       const float* __restrict__ dxx,
                                                       const float* __restrict__ dyy,
                                                       float* __restrict__ out) {
    __shared__ float sl[512];
    __shared__ float sa[512];
    int q = threadIdx.x;
    float bl = 0.f, fl = 0.f;
    if (q < NQ) {
        float dxxq = dxx[q];
        int cq = q / NQPC;
        float dd[NCLASS];
#pragma unroll
        for (int m = 0; m < NCLASS; m++)
            dd[m] = dxy[q * NCLASS + m] - 0.5f * (dxxq + dyy[m]);
        float best = dd[0];
        int bi = 0;
#pragma unroll
        for (int m = 1; m < NCLASS; m++) {
            if (dd[m] < best) { best = dd[m]; bi = m; }
        }
        float s = 0.f;
        float dcq = dd[0];
#pragma unroll
        for (int m = 0; m < NCLASS; m++) {
            s += __expf(best - dd[m]);
            if (m == cq) dcq = dd[m];
        }
        float lse = __logf(s) - best;
        bl = dcq + lse;
        out[2 + q] = bl;
        fl = (bi == cq) ? 1.f : 0.f;
    }
    sl[threadIdx.x] = bl;
    sa[threadIdx.x] = fl;
    __syncthreads();
    for (int off = 256; off; off >>= 1) {
        if (threadIdx.x < off) {
            sl[threadIdx.x] += sl[threadIdx.x + off];
            sa[threadIdx.x] += sa[threadIdx.x + off];
        }
        __syncthreads();
    }
    if (threadIdx.x == 0) {
        out[0] = sl[0] / (float)NQ;
        out[1] = sa[0] / (float)NQ;
    }
}

extern "C" void kernel_launch(void* const* d_in, const int* in_sizes, int n_in,
                              void* d_out, int out_size, void* d_ws, size_t ws_size,
                              hipStream_t stream) {
    const float* inp = (const float*)d_in[0];
    const int* target = (const int*)d_in[1];
    float* out = (float*)d_out;
    char* ws = (char*)d_ws;

    size_t off = 0;
    auto carve = [&](size_t bytes) {
        void* p = ws + off;
        off = (off + bytes + 255) & ~(size_t)255;
        return p;
    };
    int* order = (int*)carve(NTOT * sizeof(int));
    int* qsrc = (int*)carve(NQ * sizeof(int));
    float* x2 = (float*)carve((size_t)NQROWS * sizeof(float));
    float* y2 = (float*)carve((size_t)NPROWS * sizeof(float));
    float* xy = (float*)carve((size_t)NQROWS * NPROWS * sizeof(float));  // 41 MB
    float* gxx = (float*)carve((size_t)NQ * T * T * sizeof(float));
    float* gyy = (float*)carve((size_t)NCLASS * T * T * sizeof(float));
    float* dxy = (float*)carve((size_t)NQ * NCLASS * sizeof(float));
    float* dxx = (float*)carve((size_t)NQ * sizeof(float));
    float* dyy = (float*)carve((size_t)NCLASS * sizeof(float));
    half8* Ah = (half8*)carve((size_t)NQROWS * 256 * 16);  // 65.5 MB row-major
    half8* Bh = (half8*)carve((size_t)NPROWS * 256 * 16);  // 2.6 MB
    half8* Bl = (half8*)carve((size_t)NPROWS * 256 * 16);
    (void)ws_size;

    sort_kernel<<<1, 640, 0, stream>>>(target, order, qsrc);
    stage_kernel<<<STAGE_BLKS, 512, 0, stream>>>(inp, qsrc, order, Ah, Bh, Bl);
    gemm_syrk_kernel<<<SYRK_BLKS_PAD + GEMM_BLKS, 256, 0, stream>>>(Ah, Bh, Bl, xy, gxx, gyy);
    diag_kernel<<<(NQROWS + NPROWS + 255) / 256, 256, 0, stream>>>(gxx, gyy, x2, y2);
    softdtw_wave_kernel<<<(NMM + 7) / 8, 256, 0, stream>>>(xy, gxx, gyy, x2, y2, dxy, dxx, dyy);
    finalize_kernel<<<1, 512, 0, stream>>>(dxy, dxx, dyy, out);
}

// Round 14
// 255.014 us; speedup vs baseline: 1.7104x; 1.5803x over previous
//
#include <hip/hip_runtime.h>

#define T 32
#define C 2048
#define NTOT 600
#define NCLASS 20
#define NSUP 5
#define PER 30
#define NQPC 25
#define NQ 500
#define NQROWS (NQ * T)      // 16000
#define NPROWS (NCLASS * T)  // 640
#define GAMMA 0.1f
#define INVG 10.0f
#define BIG 1e10f
#define NMM (NQ * NCLASS + NQ + NCLASS)  // 10520
#define GEMM_BLKS 1250      // (16000/64) x (640/128) tiles
#define SYRK_BLKS_PAD 136   // multiple of 8 so gemm swizzle sees o%8 unchanged
#define STAGE_BLKS_A 2000   // (16000/16 rows) x 2 halves
#define STAGE_BLKS_B 80     // (640/16) x 2

typedef __fp16 half8 __attribute__((ext_vector_type(8)));
typedef float f32x4 __attribute__((ext_vector_type(4)));

// ---------------- parallel stable counting sort (1 block) ----------------
__global__ __launch_bounds__(640) void sort_kernel(const int* __restrict__ target,
                                                   int* __restrict__ order,
                                                   int* __restrict__ qsrc) {
    __shared__ int tgt[NTOT];
    __shared__ int offs[NCLASS];
    __shared__ int ordl[NTOT];
    int tid = threadIdx.x;
    if (tid < NTOT) tgt[tid] = target[tid];
    __syncthreads();
    if (tid < NCLASS) {
        int o = 0;
        for (int i = 0; i < NTOT; i++) o += (tgt[i] < tid) ? 1 : 0;
        offs[tid] = o;
    }
    __syncthreads();
    if (tid < NTOT) {
        int c = tgt[tid];
        int rank = 0;
        for (int k = 0; k < NTOT; k++) rank += (k < tid && tgt[k] == c) ? 1 : 0;
        ordl[offs[c] + rank] = tid;
    }
    __syncthreads();
    if (tid < NTOT) order[tid] = ordl[tid];
    if (tid < NQ) qsrc[tid] = ordl[(tid / NQPC) * PER + NSUP + (tid % NQPC)];
}

// ---------------- streaming staging: gather/mean + f16 split (R10 mapping) --------
// A side: hi only (f16 rounding). B side: hi + lo. CHUNK-MAJOR dst[chunk*nrows+row].
__global__ __launch_bounds__(512) void stage_kernel(const float* __restrict__ inp,
                                                    const int* __restrict__ qsrc,
                                                    const int* __restrict__ order,
                                                    half8* __restrict__ Ah,
                                                    half8* __restrict__ Bh,
                                                    half8* __restrict__ Bl) {
    int bid = blockIdx.x;
    int tid = threadIdx.x;
    int row = tid & 15, seg = tid >> 4;  // seg 0..31
    bool isA = bid < STAGE_BLKS_A;
    int b = isA ? bid : bid - STAGE_BLKS_A;
    int rowblk = b >> 1, half = b & 1;
    int rowg = rowblk * 16 + row;
    int col0 = half * 1024 + seg * 32;
    int chunk0 = half * 128 + seg * 4;
    float vals[32];
    if (isA) {
        const float* src = inp + (size_t)qsrc[rowg >> 5] * (T * C) + (size_t)(rowg & 31) * C + col0;
#pragma unroll
        for (int i = 0; i < 8; i++) {
            float4 v = *(const float4*)(src + i * 4);
            vals[i * 4 + 0] = v.x; vals[i * 4 + 1] = v.y;
            vals[i * 4 + 2] = v.z; vals[i * 4 + 3] = v.w;
        }
        half8 hv[4];
#pragma unroll
        for (int e = 0; e < 32; e++) hv[e >> 3][e & 7] = (__fp16)vals[e];
#pragma unroll
        for (int c = 0; c < 4; c++) Ah[(size_t)(chunk0 + c) * NQROWS + rowg] = hv[c];
    } else {
        int cls = rowg >> 5, trow = rowg & 31;
        const float* base = inp + (size_t)trow * C + col0;
        const float* s0 = base + (size_t)order[cls * PER + 0] * (T * C);
        const float* s1 = base + (size_t)order[cls * PER + 1] * (T * C);
        const float* s2 = base + (size_t)order[cls * PER + 2] * (T * C);
        const float* s3 = base + (size_t)order[cls * PER + 3] * (T * C);
        const float* s4 = base + (size_t)order[cls * PER + 4] * (T * C);
#pragma unroll
        for (int i = 0; i < 8; i++) {
            float4 a = *(const float4*)(s0 + i * 4);
            float4 b4 = *(const float4*)(s1 + i * 4);
            float4 c = *(const float4*)(s2 + i * 4);
            float4 d = *(const float4*)(s3 + i * 4);
            float4 e = *(const float4*)(s4 + i * 4);
            vals[i * 4 + 0] = (a.x + b4.x + c.x + d.x + e.x) * 0.2f;
            vals[i * 4 + 1] = (a.y + b4.y + c.y + d.y + e.y) * 0.2f;
            vals[i * 4 + 2] = (a.z + b4.z + c.z + d.z + e.z) * 0.2f;
            vals[i * 4 + 3] = (a.w + b4.w + c.w + d.w + e.w) * 0.2f;
        }
        half8 hv[4], lv[4];
#pragma unroll
        for (int e = 0; e < 32; e++) {
            float f = vals[e];
            __fp16 h = (__fp16)f;
            hv[e >> 3][e & 7] = h;
            lv[e >> 3][e & 7] = (__fp16)(f - (float)h);
        }
#pragma unroll
        for (int c = 0; c < 4; c++) {
            size_t o = (size_t)(chunk0 + c) * NPROWS + rowg;
            Bh[o] = hv[c];
            Bl[o] = lv[c];
        }
    }
}

// ---------------- merged: SYRK (blocks 0..135) + split-M register-direct f16 GEMM --
// GEMM: NO LDS, NO barriers (R10 structure). Block tile 64x128, wave tile 32x64 ->
// grid 1250 gemm blocks = 2x the resident waves of R10 for latency hiding.
__global__ __launch_bounds__(256) void gemm_syrk_kernel(const half8* __restrict__ Ah,
                                                        const half8* __restrict__ Bh,
                                                        const half8* __restrict__ Bl,
                                                        float* __restrict__ xy,
                                                        float* __restrict__ gxx,
                                                        float* __restrict__ gyy) {
    int tid = threadIdx.x, lane = tid & 63, wid = tid >> 6;
    int o = blockIdx.x;
    int g = lane >> 4, r = lane & 15;
    if (o < SYRK_BLKS_PAD) {
        // ---- SYRK path: one wave per 32x32 Gram matrix (short blocks first) ----
        int ww = o * 4 + wid;
        if (ww >= NQ + NCLASS) return;
        f32x4 acc[2][2];
        f32x4 zero = {0.f, 0.f, 0.f, 0.f};
        acc[0][0] = zero; acc[0][1] = zero; acc[1][0] = zero; acc[1][1] = zero;
        float* outp;
        if (ww < NQ) {
            // gxx = Ah Ah^T  (1-term: self-consistent with 2-term xy)
            int row0 = ww * 32;
            outp = gxx + (size_t)ww * (T * T);
            for (int t = 0; t < C / 32; t++) {
                size_t base = (size_t)(t * 4 + g) * NQROWS + row0 + r;
                half8 h0 = Ah[base], h1 = Ah[base + 16];
                acc[0][0] = __builtin_amdgcn_mfma_f32_16x16x32_f16(h0, h0, acc[0][0], 0, 0, 0);
                acc[0][1] = __builtin_amdgcn_mfma_f32_16x16x32_f16(h0, h1, acc[0][1], 0, 0, 0);
                acc[1][0] = __builtin_amdgcn_mfma_f32_16x16x32_f16(h1, h0, acc[1][0], 0, 0, 0);
                acc[1][1] = __builtin_amdgcn_mfma_f32_16x16x32_f16(h1, h1, acc[1][1], 0, 0, 0);
            }
        } else {
            // gyy = (Bh+Bl)(Bh+Bl)^T, 3-term
            int row0 = (ww - NQ) * 32;
            outp = gyy + (size_t)(ww - NQ) * (T * T);
            for (int t = 0; t < C / 32; t++) {
                size_t base = (size_t)(t * 4 + g) * NPROWS + row0 + r;
                half8 h0 = Bh[base], h1 = Bh[base + 16];
                half8 l0 = Bl[base], l1 = Bl[base + 16];
                acc[0][0] = __builtin_amdgcn_mfma_f32_16x16x32_f16(h0, h0, acc[0][0], 0, 0, 0);
                acc[0][0] = __builtin_amdgcn_mfma_f32_16x16x32_f16(h0, l0, acc[0][0], 0, 0, 0);
                acc[0][0] = __builtin_amdgcn_mfma_f32_16x16x32_f16(l0, h0, acc[0][0], 0, 0, 0);
                acc[0][1] = __builtin_amdgcn_mfma_f32_16x16x32_f16(h0, h1, acc[0][1], 0, 0, 0);
                acc[0][1] = __builtin_amdgcn_mfma_f32_16x16x32_f16(h0, l1, acc[0][1], 0, 0, 0);
                acc[0][1] = __builtin_amdgcn_mfma_f32_16x16x32_f16(l0, h1, acc[0][1], 0, 0, 0);
                acc[1][0] = __builtin_amdgcn_mfma_f32_16x16x32_f16(h1, h0, acc[1][0], 0, 0, 0);
                acc[1][0] = __builtin_amdgcn_mfma_f32_16x16x32_f16(h1, l0, acc[1][0], 0, 0, 0);
                acc[1][0] = __builtin_amdgcn_mfma_f32_16x16x32_f16(l1, h0, acc[1][0], 0, 0, 0);
                acc[1][1] = __builtin_amdgcn_mfma_f32_16x16x32_f16(h1, h1, acc[1][1], 0, 0, 0);
                acc[1][1] = __builtin_amdgcn_mfma_f32_16x16x32_f16(h1, l1, acc[1][1], 0, 0, 0);
                acc[1][1] = __builtin_amdgcn_mfma_f32_16x16x32_f16(l1, h1, acc[1][1], 0, 0, 0);
            }
        }
#pragma unroll
        for (int mi = 0; mi < 2; mi++)
#pragma unroll
            for (int ni = 0; ni < 2; ni++)
#pragma unroll
                for (int j = 0; j < 4; j++)
                    outp[(mi * 16 + g * 4 + j) * T + ni * 16 + r] = acc[mi][ni][j];
        return;
    }
    // ---- GEMM path: xy = Ah*(Bh+Bl)^T, 2 MFMA terms, register-direct, split-M ----
    int oo = o - SYRK_BLKS_PAD;  // 0..1249; SYRK_BLKS_PAD%8==0 keeps oo%8==o%8
    // bijective XCD swizzle over 1250 = 8*156+2 (m204 formula)
    int xcd = oo & 7, slot = oo >> 3;
    int v = (xcd < 2 ? xcd * 157 : 2 * 157 + (xcd - 2) * 156) + slot;
    int bm = v / 5, bn = v % 5;      // bm 0..249 (64-row tiles), bn 0..4 (128-col tiles)
    int wr = wid >> 1, wc = wid & 1;
    int m0 = bm * 64 + wr * 32, n0 = bn * 128 + wc * 64;  // wave tile 32x64
    const half8* pA = Ah + (size_t)g * NQROWS + m0 + r;
    const half8* pBh = Bh + (size_t)g * NPROWS + n0 + r;
    const half8* pBl = Bl + (size_t)g * NPROWS + n0 + r;
    f32x4 acc[2][4];
    f32x4 zero = {0.f, 0.f, 0.f, 0.f};
#pragma unroll
    for (int mi = 0; mi < 2; mi++)
#pragma unroll
        for (int ni = 0; ni < 4; ni++) acc[mi][ni] = zero;
#pragma unroll 2
    for (int t = 0; t < C / 32; t++) {
        half8 ah[2], bh[4], bl[4];
        ah[0] = pA[0];
        ah[1] = pA[16];
#pragma unroll
        for (int i = 0; i < 4; i++) {
            bh[i] = pBh[i * 16];
            bl[i] = pBl[i * 16];
        }
        pA += 4 * NQROWS;
        pBh += 4 * NPROWS;
        pBl += 4 * NPROWS;
#pragma unroll
        for (int mi = 0; mi < 2; mi++)
#pragma unroll
            for (int ni = 0; ni < 4; ni++) {
                acc[mi][ni] = __builtin_amdgcn_mfma_f32_16x16x32_f16(ah[mi], bh[ni], acc[mi][ni], 0, 0, 0);
                acc[mi][ni] = __builtin_amdgcn_mfma_f32_16x16x32_f16(ah[mi], bl[ni], acc[mi][ni], 0, 0, 0);
            }
    }
    int orow = m0 + g * 4;
    int ocol = n0 + r;
#pragma unroll
    for (int mi = 0; mi < 2; mi++)
#pragma unroll
        for (int ni = 0; ni < 4; ni++)
#pragma unroll
            for (int j = 0; j < 4; j++)
                xy[(size_t)(orow + mi * 16 + j) * NPROWS + ocol + ni * 16] = acc[mi][ni][j];
}

// ---------------- extract row norms from Gram diagonals ----------------
__global__ void diag_kernel(const float* __restrict__ gxx, const float* __restrict__ gyy,
                            float* __restrict__ x2, float* __restrict__ y2) {
    int i = blockIdx.x * 256 + threadIdx.x;
    if (i < NQROWS) {
        x2[i] = gxx[(size_t)(i >> 5) * (T * T) + (i & 31) * (T + 1)];
    } else if (i < NQROWS + NPROWS) {
        int j = i - NQROWS;
        y2[j] = gyy[(size_t)(j >> 5) * (T * T) + (j & 31) * (T + 1)];
    }
}

// ---------------- wavefront soft-DTW: 32 lanes = 32 columns, 2 matrices/wave ------
__global__ __launch_bounds__(256) void softdtw_wave_kernel(
        const float* __restrict__ xy, const float* __restrict__ gxx,
        const float* __restrict__ gyy, const float* __restrict__ x2,
        const float* __restrict__ y2, float* __restrict__ dxy,
        float* __restrict__ dxx, float* __restrict__ dyy) {
    int tid = threadIdx.x;
    int j = tid & 31;                       // column within the matrix
    int mm = blockIdx.x * 8 + (tid >> 5);   // 8 matrices per 256-thread block
    bool valid = mm < NMM;
    int mmc = valid ? mm : 0;
    const float* rterm;
    const float* cterm;
    const float* cptr;
    int cstride;
    float* outp;
    if (mmc < NQ * NCLASS) {
        int q = mmc / NCLASS, m = mmc % NCLASS;
        rterm = x2 + q * T;
        cterm = y2 + m * T;
        cptr = xy + (size_t)(q * T) * NPROWS + m * T;
        cstride = NPROWS;
        outp = dxy + mmc;
    } else if (mmc < NQ * NCLASS + NQ) {
        int i = mmc - NQ * NCLASS;
        rterm = x2 + i * T;
        cterm = rterm;
        cptr = gxx + (size_t)i * (T * T);
        cstride = T;
        outp = dxx + i;
    } else {
        int i = mmc - NQ * NCLASS - NQ;
        rterm = y2 + i * T;
        cterm = rterm;
        cptr = gyy + (size_t)i * (T * T);
        cstride = T;
        outp = dyy + i;
    }
    float cjv = cterm[j];      // column term (lane-resident)
    float xreg = rterm[j];     // lane l holds rterm[l]; shuffled per step
    float my_prev = BIG, my_prev2 = BIG;
    int ip = 0 - j; ip = ip < 0 ? 0 : (ip > 31 ? 31 : ip);
    float nxt_xy = cptr[(size_t)ip * cstride + j];
    for (int k = 0; k < 63; k++) {
        float cur_xy = nxt_xy;
        int in = k + 1 - j; in = in < 0 ? 0 : (in > 31 ? 31 : in);
        nxt_xy = cptr[(size_t)in * cstride + j];   // prefetch next anti-diagonal
        float lp = __shfl_up(my_prev, 1, 32);
        float dg = __shfl_up(my_prev2, 1, 32);
        if (j == 0) { lp = BIG; dg = (k == 0) ? 0.f : BIG; }
        float up = my_prev;
        int i = k - j;
        float ai = __shfl(xreg, i & 31, 32);
        float d = ai + cjv - 2.0f * cur_xy;
        float mn = fminf(dg, fminf(up, lp));
        float ssum = __expf((mn - dg) * INVG) + __expf((mn - up) * INVG) +
                     __expf((mn - lp) * INVG);
        float r = d + mn - GAMMA * __logf(ssum);
        bool active = (i >= 0) && (i < 32);
        my_prev2 = my_prev;
        my_prev = active ? r : my_prev;
    }
    if (j == 31 && valid) *outp = my_prev;  // R[31][31]
}

// ---------------- finalize: dist, log-softmax, loss, acc ----------------
__global__ __launch_bounds__(512) void finalize_kernel(const float* __restrict__ dxy,
                                                       const float* __restrict__ dxx,
                                                       const float* __restrict__ dyy,
                                                       float* __restrict__ out) {
    __shared__ float sl[512];
    __shared__ float sa[512];
    int q = threadIdx.x;
    float bl = 0.f, fl = 0.f;
    if (q < NQ) {
        float dxxq = dxx[q];
        int cq = q / NQPC;
        float dd[NCLASS];
#pragma unroll
        for (int m = 0; m < NCLASS; m++)
            dd[m] = dxy[q * NCLASS + m] - 0.5f * (dxxq + dyy[m]);
        float best = dd[0];
        int bi = 0;
#pragma unroll
        for (int m = 1; m < NCLASS; m++) {
            if (dd[m] < best) { best = dd[m]; bi = m; }
        }
        float s = 0.f;
        float dcq = dd[0];
#pragma unroll
        for (int m = 0; m < NCLASS; m++) {
            s += __expf(best - dd[m]);
            if (m == cq) dcq = dd[m];
        }
        float lse = __logf(s) - best;
        bl = dcq + lse;
        out[2 + q] = bl;
        fl = (bi == cq) ? 1.f : 0.f;
    }
    sl[threadIdx.x] = bl;
    sa[threadIdx.x] = fl;
    __syncthreads();
    for (int off = 256; off; off >>= 1) {
        if (threadIdx.x < off) {
            sl[threadIdx.x] += sl[threadIdx.x + off];
            sa[threadIdx.x] += sa[threadIdx.x + off];
        }
        __syncthreads();
    }
    if (threadIdx.x == 0) {
        out[0] = sl[0] / (float)NQ;
        out[1] = sa[0] / (float)NQ;
    }
}

extern "C" void kernel_launch(void* const* d_in, const int* in_sizes, int n_in,
                              void* d_out, int out_size, void* d_ws, size_t ws_size,
                              hipStream_t stream) {
    const float* inp = (const float*)d_in[0];
    const int* target = (const int*)d_in[1];
    float* out = (float*)d_out;
    char* ws = (char*)d_ws;

    size_t off = 0;
    auto carve = [&](size_t bytes) {
        void* p = ws + off;
        off = (off + bytes + 255) & ~(size_t)255;
        return p;
    };
    int* order = (int*)carve(NTOT * sizeof(int));
    int* qsrc = (int*)carve(NQ * sizeof(int));
    float* x2 = (float*)carve((size_t)NQROWS * sizeof(float));
    float* y2 = (float*)carve((size_t)NPROWS * sizeof(float));
    float* xy = (float*)carve((size_t)NQROWS * NPROWS * sizeof(float));  // 41 MB
    float* gxx = (float*)carve((size_t)NQ * T * T * sizeof(float));
    float* gyy = (float*)carve((size_t)NCLASS * T * T * sizeof(float));
    float* dxy = (float*)carve((size_t)NQ * NCLASS * sizeof(float));
    float* dxx = (float*)carve((size_t)NQ * sizeof(float));
    float* dyy = (float*)carve((size_t)NCLASS * sizeof(float));
    half8* Ah = (half8*)carve((size_t)(C / 8) * NQROWS * 16);  // 65.5 MB chunk-major
    half8* Bh = (half8*)carve((size_t)(C / 8) * NPROWS * 16);  // 2.6 MB
    half8* Bl = (half8*)carve((size_t)(C / 8) * NPROWS * 16);
    (void)ws_size;

    sort_kernel<<<1, 640, 0, stream>>>(target, order, qsrc);
    stage_kernel<<<STAGE_BLKS_A + STAGE_BLKS_B, 512, 0, stream>>>(inp, qsrc, order, Ah, Bh, Bl);
    gemm_syrk_kernel<<<SYRK_BLKS_PAD + GEMM_BLKS, 256, 0, stream>>>(Ah, Bh, Bl, xy, gxx, gyy);
    diag_kernel<<<(NQROWS + NPROWS + 255) / 256, 256, 0, stream>>>(gxx, gyy, x2, y2);
    softdtw_wave_kernel<<<(NMM + 7) / 8, 256, 0, stream>>>(xy, gxx, gyy, x2, y2, dxy, dxx, dyy);
    finalize_kernel<<<1, 512, 0, stream>>>(dxy, dxx, dyy, out);
}

// Round 15
// 194.446 us; speedup vs baseline: 2.2431x; 1.3115x over previous
//
#include <hip/hip_runtime.h>

#define T 32
#define C 2048
#define NTOT 600
#define NCLASS 20
#define NSUP 5
#define PER 30
#define NQPC 25
#define NQ 500
#define NQROWS (NQ * T)      // 16000
#define NPROWS (NCLASS * T)  // 640
#define GAMMA 0.1f
#define INVG 10.0f
#define BIG 1e10f
#define NMM (NQ * NCLASS + NQ + NCLASS)  // 10520
#define GEMM_BLKS 625
#define SYRK_BLKS_PAD 136  // multiple of 8 so gemm swizzle sees o%8 unchanged
#define STAGE_BLKS_A 2000  // (16000/16 rows) x 2 halves
#define STAGE_BLKS_B 80    // (640/16) x 2

typedef __fp16 half8 __attribute__((ext_vector_type(8)));
typedef float f32x4 __attribute__((ext_vector_type(4)));

// ---------------- parallel stable counting sort (1 block) ----------------
__global__ __launch_bounds__(640) void sort_kernel(const int* __restrict__ target,
                                                   int* __restrict__ order,
                                                   int* __restrict__ qsrc) {
    __shared__ int tgt[NTOT];
    __shared__ int offs[NCLASS];
    __shared__ int ordl[NTOT];
    int tid = threadIdx.x;
    if (tid < NTOT) tgt[tid] = target[tid];
    __syncthreads();
    if (tid < NCLASS) {
        int o = 0;
        for (int i = 0; i < NTOT; i++) o += (tgt[i] < tid) ? 1 : 0;
        offs[tid] = o;
    }
    __syncthreads();
    if (tid < NTOT) {
        int c = tgt[tid];
        int rank = 0;
        for (int k = 0; k < NTOT; k++) rank += (k < tid && tgt[k] == c) ? 1 : 0;
        ordl[offs[c] + rank] = tid;
    }
    __syncthreads();
    if (tid < NTOT) order[tid] = ordl[tid];
    if (tid < NQ) qsrc[tid] = ordl[(tid / NQPC) * PER + NSUP + (tid % NQPC)];
}

// ---------------- streaming staging: gather/mean + f16 round (R10 mapping) --------
// Both sides f16 hi only -> cost matrices are EXACT sq-distances of rounded vectors.
// CHUNK-MAJOR dst[chunk*nrows+row].
__global__ __launch_bounds__(512) void stage_kernel(const float* __restrict__ inp,
                                                    const int* __restrict__ qsrc,
                                                    const int* __restrict__ order,
                                                    half8* __restrict__ Ah,
                                                    half8* __restrict__ Bh) {
    int bid = blockIdx.x;
    int tid = threadIdx.x;
    int row = tid & 15, seg = tid >> 4;  // seg 0..31
    bool isA = bid < STAGE_BLKS_A;
    int b = isA ? bid : bid - STAGE_BLKS_A;
    int rowblk = b >> 1, half = b & 1;
    int rowg = rowblk * 16 + row;
    int col0 = half * 1024 + seg * 32;
    int chunk0 = half * 128 + seg * 4;
    float vals[32];
    if (isA) {
        const float* src = inp + (size_t)qsrc[rowg >> 5] * (T * C) + (size_t)(rowg & 31) * C + col0;
#pragma unroll
        for (int i = 0; i < 8; i++) {
            float4 v = *(const float4*)(src + i * 4);
            vals[i * 4 + 0] = v.x; vals[i * 4 + 1] = v.y;
            vals[i * 4 + 2] = v.z; vals[i * 4 + 3] = v.w;
        }
        half8 hv[4];
#pragma unroll
        for (int e = 0; e < 32; e++) hv[e >> 3][e & 7] = (__fp16)vals[e];
#pragma unroll
        for (int c = 0; c < 4; c++) Ah[(size_t)(chunk0 + c) * NQROWS + rowg] = hv[c];
    } else {
        int cls = rowg >> 5, trow = rowg & 31;
        const float* base = inp + (size_t)trow * C + col0;
        const float* s0 = base + (size_t)order[cls * PER + 0] * (T * C);
        const float* s1 = base + (size_t)order[cls * PER + 1] * (T * C);
        const float* s2 = base + (size_t)order[cls * PER + 2] * (T * C);
        const float* s3 = base + (size_t)order[cls * PER + 3] * (T * C);
        const float* s4 = base + (size_t)order[cls * PER + 4] * (T * C);
#pragma unroll
        for (int i = 0; i < 8; i++) {
            float4 a = *(const float4*)(s0 + i * 4);
            float4 b4 = *(const float4*)(s1 + i * 4);
            float4 c = *(const float4*)(s2 + i * 4);
            float4 d = *(const float4*)(s3 + i * 4);
            float4 e = *(const float4*)(s4 + i * 4);
            vals[i * 4 + 0] = (a.x + b4.x + c.x + d.x + e.x) * 0.2f;
            vals[i * 4 + 1] = (a.y + b4.y + c.y + d.y + e.y) * 0.2f;
            vals[i * 4 + 2] = (a.z + b4.z + c.z + d.z + e.z) * 0.2f;
            vals[i * 4 + 3] = (a.w + b4.w + c.w + d.w + e.w) * 0.2f;
        }
        half8 hv[4];
#pragma unroll
        for (int e = 0; e < 32; e++) hv[e >> 3][e & 7] = (__fp16)vals[e];
#pragma unroll
        for (int c = 0; c < 4; c++) Bh[(size_t)(chunk0 + c) * NPROWS + rowg] = hv[c];
    }
}

// ---------------- merged: SYRK (blocks 0..135) + 1-term register-direct f16 GEMM --
// R10 structure: NO LDS, NO barriers, compiler-scheduled. Bh (2.6MB) is L2-resident.
__global__ __launch_bounds__(256) void gemm_syrk_kernel(const half8* __restrict__ Ah,
                                                        const half8* __restrict__ Bh,
                                                        float* __restrict__ xy,
                                                        float* __restrict__ gxx,
                                                        float* __restrict__ gyy) {
    int tid = threadIdx.x, lane = tid & 63, wid = tid >> 6;
    int o = blockIdx.x;
    int g = lane >> 4, r = lane & 15;
    if (o < SYRK_BLKS_PAD) {
        // ---- SYRK path: one wave per 32x32 Gram matrix (short blocks first) ----
        int ww = o * 4 + wid;
        if (ww >= NQ + NCLASS) return;
        const half8* hi;
        int nrows, row0;
        float* outp;
        if (ww < NQ) {
            hi = Ah; nrows = NQROWS; row0 = ww * 32;
            outp = gxx + (size_t)ww * (T * T);
        } else {
            hi = Bh; nrows = NPROWS; row0 = (ww - NQ) * 32;
            outp = gyy + (size_t)(ww - NQ) * (T * T);
        }
        f32x4 acc[2][2];
        f32x4 zero = {0.f, 0.f, 0.f, 0.f};
        acc[0][0] = zero; acc[0][1] = zero; acc[1][0] = zero; acc[1][1] = zero;
        for (int t = 0; t < C / 32; t++) {
            size_t base = (size_t)(t * 4 + g) * nrows + row0 + r;
            half8 h0 = hi[base], h1 = hi[base + 16];
            acc[0][0] = __builtin_amdgcn_mfma_f32_16x16x32_f16(h0, h0, acc[0][0], 0, 0, 0);
            acc[0][1] = __builtin_amdgcn_mfma_f32_16x16x32_f16(h0, h1, acc[0][1], 0, 0, 0);
            acc[1][0] = __builtin_amdgcn_mfma_f32_16x16x32_f16(h1, h0, acc[1][0], 0, 0, 0);
            acc[1][1] = __builtin_amdgcn_mfma_f32_16x16x32_f16(h1, h1, acc[1][1], 0, 0, 0);
        }
#pragma unroll
        for (int mi = 0; mi < 2; mi++)
#pragma unroll
            for (int ni = 0; ni < 2; ni++)
#pragma unroll
                for (int j = 0; j < 4; j++)
                    outp[(mi * 16 + g * 4 + j) * T + ni * 16 + r] = acc[mi][ni][j];
        return;
    }
    // ---- GEMM path: xy = Ah*Bh^T, 1 MFMA term, register-direct ----
    int oo = o - SYRK_BLKS_PAD;  // 0..624; SYRK_BLKS_PAD%8==0 keeps oo%8==o%8
    int xcd = oo & 7, slot = oo >> 3;
    int v = (xcd < 1 ? xcd * 79 : 79 + (xcd - 1) * 78) + slot;  // bijective over 625=8*78+1
    int bm = v / 5, bn = v % 5;
    int wr = wid >> 1, wc = wid & 1;
    int m0 = bm * 128 + wr * 64, n0 = bn * 128 + wc * 64;  // this wave's 64x64 tile
    const half8* pA = Ah + (size_t)g * NQROWS + m0 + r;
    const half8* pB = Bh + (size_t)g * NPROWS + n0 + r;
    f32x4 acc[4][4];
    f32x4 zero = {0.f, 0.f, 0.f, 0.f};
#pragma unroll
    for (int mi = 0; mi < 4; mi++)
#pragma unroll
        for (int ni = 0; ni < 4; ni++) acc[mi][ni] = zero;
#pragma unroll 2
    for (int t = 0; t < C / 32; t++) {
        half8 ah[4], bh[4];
#pragma unroll
        for (int i = 0; i < 4; i++) {
            ah[i] = pA[i * 16];    // imm offsets 0,256,512,768 B
            bh[i] = pB[i * 16];
        }
        pA += 4 * NQROWS;
        pB += 4 * NPROWS;
#pragma unroll
        for (int mi = 0; mi < 4; mi++)
#pragma unroll
            for (int ni = 0; ni < 4; ni++)
                acc[mi][ni] = __builtin_amdgcn_mfma_f32_16x16x32_f16(ah[mi], bh[ni], acc[mi][ni], 0, 0, 0);
    }
    int orow = m0 + g * 4;
    int ocol = n0 + r;
#pragma unroll
    for (int mi = 0; mi < 4; mi++)
#pragma unroll
        for (int ni = 0; ni < 4; ni++)
#pragma unroll
            for (int j = 0; j < 4; j++)
                xy[(size_t)(orow + mi * 16 + j) * NPROWS + ocol + ni * 16] = acc[mi][ni][j];
}

// ---------------- extract row norms from Gram diagonals ----------------
__global__ void diag_kernel(const float* __restrict__ gxx, const float* __restrict__ gyy,
                            float* __restrict__ x2, float* __restrict__ y2) {
    int i = blockIdx.x * 256 + threadIdx.x;
    if (i < NQROWS) {
        x2[i] = gxx[(size_t)(i >> 5) * (T * T) + (i & 31) * (T + 1)];
    } else if (i < NQROWS + NPROWS) {
        int j = i - NQROWS;
        y2[j] = gyy[(size_t)(j >> 5) * (T * T) + (j & 31) * (T + 1)];
    }
}

// ---------------- wavefront soft-DTW: 32 lanes = 32 columns, 2 matrices/wave ------
__global__ __launch_bounds__(256) void softdtw_wave_kernel(
        const float* __restrict__ xy, const float* __restrict__ gxx,
        const float* __restrict__ gyy, const float* __restrict__ x2,
        const float* __restrict__ y2, float* __restrict__ dxy,
        float* __restrict__ dxx, float* __restrict__ dyy) {
    int tid = threadIdx.x;
    int j = tid & 31;                       // column within the matrix
    int mm = blockIdx.x * 8 + (tid >> 5);   // 8 matrices per 256-thread block
    bool valid = mm < NMM;
    int mmc = valid ? mm : 0;
    const float* rterm;
    const float* cterm;
    const float* cptr;
    int cstride;
    float* outp;
    if (mmc < NQ * NCLASS) {
        int q = mmc / NCLASS, m = mmc % NCLASS;
        rterm = x2 + q * T;
        cterm = y2 + m * T;
        cptr = xy + (size_t)(q * T) * NPROWS + m * T;
        cstride = NPROWS;
        outp = dxy + mmc;
    } else if (mmc < NQ * NCLASS + NQ) {
        int i = mmc - NQ * NCLASS;
        rterm = x2 + i * T;
        cterm = rterm;
        cptr = gxx + (size_t)i * (T * T);
        cstride = T;
        outp = dxx + i;
    } else {
        int i = mmc - NQ * NCLASS - NQ;
        rterm = y2 + i * T;
        cterm = rterm;
        cptr = gyy + (size_t)i * (T * T);
        cstride = T;
        outp = dyy + i;
    }
    float cjv = cterm[j];      // column term (lane-resident)
    float xreg = rterm[j];     // lane l holds rterm[l]; shuffled per step
    float my_prev = BIG, my_prev2 = BIG;
    int ip = 0 - j; ip = ip < 0 ? 0 : (ip > 31 ? 31 : ip);
    float nxt_xy = cptr[(size_t)ip * cstride + j];
    for (int k = 0; k < 63; k++) {
        float cur_xy = nxt_xy;
        int in = k + 1 - j; in = in < 0 ? 0 : (in > 31 ? 31 : in);
        nxt_xy = cptr[(size_t)in * cstride + j];   // prefetch next anti-diagonal
        float lp = __shfl_up(my_prev, 1, 32);
        float dg = __shfl_up(my_prev2, 1, 32);
        if (j == 0) { lp = BIG; dg = (k == 0) ? 0.f : BIG; }
        float up = my_prev;
        int i = k - j;
        float ai = __shfl(xreg, i & 31, 32);
        float d = ai + cjv - 2.0f * cur_xy;
        float mn = fminf(dg, fminf(up, lp));
        float ssum = __expf((mn - dg) * INVG) + __expf((mn - up) * INVG) +
                     __expf((mn - lp) * INVG);
        float r = d + mn - GAMMA * __logf(ssum);
        bool active = (i >= 0) && (i < 32);
        my_prev2 = my_prev;
        my_prev = active ? r : my_prev;
    }
    if (j == 31 && valid) *outp = my_prev;  // R[31][31]
}

// ---------------- finalize: dist, log-softmax, loss, acc ----------------
__global__ __launch_bounds__(512) void finalize_kernel(const float* __restrict__ dxy,
                                                       const float* __restrict__ dxx,
                                                       const float* __restrict__ dyy,
                                                       float* __restrict__ out) {
    __shared__ float sl[512];
    __shared__ float sa[512];
    int q = threadIdx.x;
    float bl = 0.f, fl = 0.f;
    if (q < NQ) {
        float dxxq = dxx[q];
        int cq = q / NQPC;
        float dd[NCLASS];
#pragma unroll
        for (int m = 0; m < NCLASS; m++)
            dd[m] = dxy[q * NCLASS + m] - 0.5f * (dxxq + dyy[m]);
        float best = dd[0];
        int bi = 0;
#pragma unroll
        for (int m = 1; m < NCLASS; m++) {
            if (dd[m] < best) { best = dd[m]; bi = m; }
        }
        float s = 0.f;
        float dcq = dd[0];
#pragma unroll
        for (int m = 0; m < NCLASS; m++) {
            s += __expf(best - dd[m]);
            if (m == cq) dcq = dd[m];
        }
        float lse = __logf(s) - best;
        bl = dcq + lse;
        out[2 + q] = bl;
        fl = (bi == cq) ? 1.f : 0.f;
    }
    sl[threadIdx.x] = bl;
    sa[threadIdx.x] = fl;
    __syncthreads();
    for (int off = 256; off; off >>= 1) {
        if (threadIdx.x < off) {
            sl[threadIdx.x] += sl[threadIdx.x + off];
            sa[threadIdx.x] += sa[threadIdx.x + off];
        }
        __syncthreads();
    }
    if (threadIdx.x == 0) {
        out[0] = sl[0] / (float)NQ;
        out[1] = sa[0] / (float)NQ;
    }
}

extern "C" void kernel_launch(void* const* d_in, const int* in_sizes, int n_in,
                              void* d_out, int out_size, void* d_ws, size_t ws_size,
                              hipStream_t stream) {
    const float* inp = (const float*)d_in[0];
    const int* target = (const int*)d_in[1];
    float* out = (float*)d_out;
    char* ws = (char*)d_ws;

    size_t off = 0;
    auto carve = [&](size_t bytes) {
        void* p = ws + off;
        off = (off + bytes + 255) & ~(size_t)255;
        return p;
    };
    int* order = (int*)carve(NTOT * sizeof(int));
    int* qsrc = (int*)carve(NQ * sizeof(int));
    float* x2 = (float*)carve((size_t)NQROWS * sizeof(float));
    float* y2 = (float*)carve((size_t)NPROWS * sizeof(float));
    float* xy = (float*)carve((size_t)NQROWS * NPROWS * sizeof(float));  // 41 MB
    float* gxx = (float*)carve((size_t)NQ * T * T * sizeof(float));
    float* gyy = (float*)carve((size_t)NCLASS * T * T * sizeof(float));
    float* dxy = (float*)carve((size_t)NQ * NCLASS * sizeof(float));
    float* dxx = (float*)carve((size_t)NQ * sizeof(float));
    float* dyy = (float*)carve((size_t)NCLASS * sizeof(float));
    half8* Ah = (half8*)carve((size_t)(C / 8) * NQROWS * 16);  // 65.5 MB chunk-major
    half8* Bh = (half8*)carve((size_t)(C / 8) * NPROWS * 16);  // 2.6 MB (L2-resident)
    (void)ws_size;

    sort_kernel<<<1, 640, 0, stream>>>(target, order, qsrc);
    stage_kernel<<<STAGE_BLKS_A + STAGE_BLKS_B, 512, 0, stream>>>(inp, qsrc, order, Ah, Bh);
    gemm_syrk_kernel<<<SYRK_BLKS_PAD + GEMM_BLKS, 256, 0, stream>>>(Ah, Bh, xy, gxx, gyy);
    diag_kernel<<<(NQROWS + NPROWS + 255) / 256, 256, 0, stream>>>(gxx, gyy, x2, y2);
    softdtw_wave_kernel<<<(NMM + 7) / 8, 256, 0, stream>>>(xy, gxx, gyy, x2, y2, dxy, dxx, dyy);
    finalize_kernel<<<1, 512, 0, stream>>>(dxy, dxx, dyy, out);
}